// Round 4
// baseline (398.460 us; speedup 1.0000x reference)
//
#include <hip/hip_runtime.h>
#include <cstdint>
#include <cstddef>

typedef unsigned short u16;
typedef __attribute__((ext_vector_type(8))) __bf16 bf16x8;
typedef __attribute__((ext_vector_type(4))) float floatx4;

#define Bz 8
#define Sz 1024
#define Dz 768
#define Hz 12
#define DHz 64

__device__ __forceinline__ u16 f2b(float f) {
  unsigned u = __float_as_uint(f);
  return (u16)((u + 0x7fffu + ((u >> 16) & 1u)) >> 16);
}

__device__ __forceinline__ bf16x8 ld8(const u16* p) {
  union { uint4 u; bf16x8 b; } t;
  t.u = *reinterpret_cast<const uint4*>(p);
  return t.b;
}

// async global->LDS, 16B per lane; lds base must be wave-uniform (HW adds lane*16)
__device__ __forceinline__ void load_lds16(const u16* g, u16* l) {
  __builtin_amdgcn_global_load_lds(
      (const __attribute__((address_space(1))) unsigned int*)g,
      (__attribute__((address_space(3))) unsigned int*)l, 16, 0, 0);
}

// ---------------- conversions ----------------
__global__ __launch_bounds__(256) void cvt4(const float* __restrict__ src,
                                            u16* __restrict__ dst, int n4) {
  int i = blockIdx.x * 256 + threadIdx.x;
  if (i >= n4) return;
  float4 v = reinterpret_cast<const float4*>(src)[i];
  union { u16 s[4]; uint2 u; } t;
  t.s[0] = f2b(v.x); t.s[1] = f2b(v.y); t.s[2] = f2b(v.z); t.s[3] = f2b(v.w);
  reinterpret_cast<uint2*>(dst)[i] = t.u;
}

// transpose fp32 [K][N] -> bf16 [N][K]; for QKV pack s1/s2 select by column
__global__ __launch_bounds__(256)
void wtrans(const float* __restrict__ s0, const float* __restrict__ s1,
            const float* __restrict__ s2, u16* __restrict__ dst,
            int K, int N, int srcN) {
  __shared__ float T[32][33];
  const int tx = threadIdx.x & 31, ty = threadIdx.x >> 5;
  const int n0 = blockIdx.x * 32, k0 = blockIdx.y * 32;
  const int n = n0 + tx;
  const float* src = s0;
  int nn = n;
  if (s1 && n >= 1536) { src = s2; nn = n - 1536; }
  else if (s1 && n >= 768) { src = s1; nn = n - 768; }
#pragma unroll
  for (int i = 0; i < 4; ++i)
    T[ty + i * 8][tx] = src[(size_t)(k0 + ty + i * 8) * srcN + nn];
  __syncthreads();
#pragma unroll
  for (int i = 0; i < 4; ++i)
    dst[(size_t)(n0 + ty + i * 8) * K + k0 + tx] = f2b(T[tx][ty + i * 8]);
}

// ---------------- GEMM (B^T input): C = A(MxK) * Bt(NxK)^T + epilogue ------
// 2-stage software pipeline: double-buffered LDS, raw s_barrier + fine vmcnt
// (no full drain at the barrier -- prefetch stays in flight across it).
// EPI 0: QKV scatter; EPI 1: bias0 + resid (fp32) -> outF; EPI 2: bias0+relu->outB
template <int EPI>
__global__ __launch_bounds__(256, 4)
void gemm_k(const u16* __restrict__ A, const u16* __restrict__ Bt,
            int M, int N, int K,
            const float* __restrict__ bias0, const float* __restrict__ bias1,
            const float* __restrict__ bias2, const float* __restrict__ resid,
            float* __restrict__ outF, u16* __restrict__ outB,
            u16* __restrict__ qO, u16* __restrict__ kO, u16* __restrict__ vtO) {
  __shared__ __align__(16) u16 As[2][128 * 32];
  __shared__ __align__(16) u16 Bs[2][128 * 32];
  const int tid = threadIdx.x;
  const int lane = tid & 63, wave = tid >> 6;
  const int l15 = lane & 15, quad = lane >> 4;
  const int m0 = blockIdx.y * 128, n0 = blockIdx.x * 128;
  const int wm = (wave >> 1) * 64, wn = (wave & 1) * 64;

  floatx4 acc[4][4];
#pragma unroll
  for (int i = 0; i < 4; ++i)
#pragma unroll
    for (int j = 0; j < 4; ++j) acc[i][j] = {0.f, 0.f, 0.f, 0.f};

  const int srow = lane >> 2;          // + (wave*2+j)*16
  const int scol = (lane & 3) * 8;
  const u16* pA = A + (size_t)(m0 + wave * 32 + srow) * K + scol;
  const u16* pB = Bt + (size_t)(n0 + wave * 32 + srow) * K + scol;

  // prologue: stage tile 0 into buf 0 (4 loads/thread in flight)
#pragma unroll
  for (int j = 0; j < 2; ++j) {
    load_lds16(pA + (size_t)(j * 16) * K, &As[0][(wave * 2 + j) * 512]);
    load_lds16(pB + (size_t)(j * 16) * K, &Bs[0][(wave * 2 + j) * 512]);
  }

  const int NIT = K >> 5;
  for (int i = 0; i < NIT; ++i) {
    const int cur = i & 1;
    // (a) all waves finished reading buf[cur^1] (iter i-1) -> safe to overwrite
    __builtin_amdgcn_s_barrier();
    if (i + 1 < NIT) {
      const int k1 = (i + 1) << 5;
#pragma unroll
      for (int j = 0; j < 2; ++j) {
        load_lds16(pA + (size_t)(j * 16) * K + k1, &As[cur ^ 1][(wave * 2 + j) * 512]);
        load_lds16(pB + (size_t)(j * 16) * K + k1, &Bs[cur ^ 1][(wave * 2 + j) * 512]);
      }
      // wait only for tile i's 4 loads (issued last iter); keep 4 in flight
      asm volatile("s_waitcnt vmcnt(4)" ::: "memory");
    } else {
      asm volatile("s_waitcnt vmcnt(0)" ::: "memory");
    }
    // (b) tile i visible to all waves
    __builtin_amdgcn_s_barrier();
    bf16x8 af[4], bf[4];
#pragma unroll
    for (int ii = 0; ii < 4; ++ii)
      af[ii] = ld8(&As[cur][(wm + ii * 16 + l15) * 32 + quad * 8]);
#pragma unroll
    for (int j = 0; j < 4; ++j)
      bf[j] = ld8(&Bs[cur][(wn + j * 16 + l15) * 32 + quad * 8]);
#pragma unroll
    for (int ii = 0; ii < 4; ++ii)
#pragma unroll
      for (int j = 0; j < 4; ++j)
        acc[ii][j] = __builtin_amdgcn_mfma_f32_16x16x32_bf16(af[ii], bf[j],
                                                             acc[ii][j], 0, 0, 0);
  }

#pragma unroll
  for (int i = 0; i < 4; ++i) {
    int mbase = m0 + wm + i * 16 + quad * 4;
#pragma unroll
    for (int j = 0; j < 4; ++j) {
      int n = n0 + wn + j * 16 + l15;
#pragma unroll
      for (int r = 0; r < 4; ++r) {
        int mm = mbase + r;
        float v = acc[i][j][r];
        if (EPI == 0) {
          if (n < 768) {
            v += bias0[n];
            qO[(size_t)mm * 768 + n] = f2b(v);
          } else if (n < 1536) {
            v += bias1[n - 768];
            kO[(size_t)mm * 768 + (n - 768)] = f2b(v);
          } else {
            int d = n - 1536;
            v += bias2[d];
            int hh = d >> 6, dh = d & 63;
            int bb = mm >> 10, ss = mm & 1023;
            vtO[((size_t)(bb * Hz + hh) * DHz + dh) * Sz + ss] = f2b(v);
          }
        } else if (EPI == 1) {
          v += bias0[n] + resid[(size_t)mm * N + n];
          outF[(size_t)mm * N + n] = v;
        } else {
          v += bias0[n];
          v = fmaxf(v, 0.f);
          outB[(size_t)mm * N + n] = f2b(v);
        }
      }
    }
  }
}

// ---------------- flash attention (LDS-staged K/V tiles) ----------------
__global__ __launch_bounds__(256, 3)
void attn_k(const u16* __restrict__ q, const u16* __restrict__ kbuf,
            const u16* __restrict__ vt, const int* __restrict__ mask,
            u16* __restrict__ ctx) {
  __shared__ float addend[Sz];
  __shared__ __align__(16) u16 Ks[128 * 64];
  __shared__ __align__(16) u16 Vs[64 * 128];
  __shared__ __align__(16) u16 P[4][16][132];
  const int tid = threadIdx.x;
  const int wave = tid >> 6, lane = tid & 63;
  const int l15 = lane & 15, quad = lane >> 4;
  const int bq = blockIdx.x;
  const int b = blockIdx.y / Hz, h = blockIdx.y % Hz;

  for (int s = tid; s < Sz; s += 256)
    addend[s] = mask[b * Sz + s] ? 0.f : -1e9f;

  const int qrow = bq * 64 + wave * 16 + l15;
  const u16* qp = q + (size_t)(b * Sz + qrow) * Dz + h * DHz;
  const bf16x8 fq0 = ld8(qp + quad * 8);
  const bf16x8 fq1 = ld8(qp + 32 + quad * 8);

  const int kchunk = (lane & 7) ^ (lane >> 3);
  const int l7 = l15 & 7;
  const int s0q = quad ^ l7;

  float m_l = -1e30f, l_l = 0.f;
  floatx4 o[4];
#pragma unroll
  for (int nt = 0; nt < 4; ++nt) o[nt] = {0.f, 0.f, 0.f, 0.f};

  const size_t vbase = (size_t)(b * Hz + h) * DHz * Sz;

  for (int kt = 0; kt < Sz / 128; ++kt) {
    __syncthreads();
#pragma unroll
    for (int j = 0; j < 4; ++j) {
      const int key = wave * 32 + j * 8 + (lane >> 3);
      load_lds16(kbuf + (size_t)(b * Sz + kt * 128 + key) * Dz + h * DHz +
                     kchunk * 8,
                 Ks + wave * 2048 + j * 512);
      const int dh = wave * 16 + j * 4 + (lane >> 4);
      const int vchunk = (lane & 15) ^ (dh & 7);
      load_lds16(vt + vbase + (size_t)dh * Sz + kt * 128 + vchunk * 8,
                 Vs + wave * 2048 + j * 512);
    }
    __syncthreads();

    floatx4 z[8];
#pragma unroll
    for (int t = 0; t < 8; ++t) {
      const int krow = t * 16 + l15;
      bf16x8 fk0 = ld8(&Ks[krow * 64 + s0q * 8]);
      bf16x8 fk1 = ld8(&Ks[krow * 64 + (s0q ^ 4) * 8]);
      floatx4 zz = {0.f, 0.f, 0.f, 0.f};
      zz = __builtin_amdgcn_mfma_f32_16x16x32_bf16(fk0, fq0, zz, 0, 0, 0);
      zz = __builtin_amdgcn_mfma_f32_16x16x32_bf16(fk1, fq1, zz, 0, 0, 0);
      const float4 ad =
          *reinterpret_cast<const float4*>(&addend[kt * 128 + t * 16 + quad * 4]);
      z[t][0] = zz[0] * 0.125f + ad.x;
      z[t][1] = zz[1] * 0.125f + ad.y;
      z[t][2] = zz[2] * 0.125f + ad.z;
      z[t][3] = zz[3] * 0.125f + ad.w;
    }
    float mx = z[0][0];
#pragma unroll
    for (int t = 0; t < 8; ++t)
#pragma unroll
      for (int r = 0; r < 4; ++r) mx = fmaxf(mx, z[t][r]);
    mx = fmaxf(mx, __shfl_xor(mx, 16, 64));
    mx = fmaxf(mx, __shfl_xor(mx, 32, 64));
    const float nm = fmaxf(m_l, mx);
    const float alpha = __expf(m_l - nm);
    m_l = nm;
    float su = 0.f;
#pragma unroll
    for (int t = 0; t < 8; ++t) {
      union { u16 s[4]; uint2 u; } pk;
#pragma unroll
      for (int r = 0; r < 4; ++r) {
        float p = __expf(z[t][r] - nm);
        su += p;
        pk.s[r] = f2b(p);
      }
      *reinterpret_cast<uint2*>(&P[wave][l15][t * 16 + quad * 4]) = pk.u;
    }
    su += __shfl_xor(su, 16, 64);
    su += __shfl_xor(su, 32, 64);
    l_l = l_l * alpha + su;
    float av[4];
#pragma unroll
    for (int r = 0; r < 4; ++r) av[r] = __shfl(alpha, quad * 4 + r, 64);
#pragma unroll
    for (int nt = 0; nt < 4; ++nt)
#pragma unroll
      for (int r = 0; r < 4; ++r) o[nt][r] *= av[r];
    bf16x8 ap[4];
#pragma unroll
    for (int c = 0; c < 4; ++c)
      ap[c] = ld8(&P[wave][l15][c * 32 + quad * 8]);
#pragma unroll
    for (int nt = 0; nt < 4; ++nt) {
#pragma unroll
      for (int c = 0; c < 4; ++c) {
        bf16x8 bv =
            ld8(&Vs[(nt * 16 + l15) * 128 + (((c * 4 + quad) ^ l7) * 8)]);
        o[nt] = __builtin_amdgcn_mfma_f32_16x16x32_bf16(ap[c], bv, o[nt], 0, 0, 0);
      }
    }
  }

  const float linv = 1.f / l_l;
  float lv[4];
#pragma unroll
  for (int r = 0; r < 4; ++r) lv[r] = __shfl(linv, quad * 4 + r, 64);
  const int qr = bq * 64 + wave * 16 + quad * 4;
#pragma unroll
  for (int nt = 0; nt < 4; ++nt)
#pragma unroll
    for (int r = 0; r < 4; ++r) {
      float v = o[nt][r] * lv[r];
      ctx[(size_t)(b * Sz + qr + r) * Dz + h * DHz + nt * 16 + l15] = f2b(v);
    }
}

// ---------------- layernorm (row = 768) ----------------
__global__ __launch_bounds__(256)
void ln_k(const float* __restrict__ in, const float* __restrict__ g,
          const float* __restrict__ be, float* __restrict__ outF,
          u16* __restrict__ outB) {
  const int row = blockIdx.x;
  const float* x = in + (size_t)row * Dz;
  const int tid = threadIdx.x;
  float v0 = x[tid], v1 = x[tid + 256], v2 = x[tid + 512];
  float s = v0 + v1 + v2;
  float s2 = v0 * v0 + v1 * v1 + v2 * v2;
#pragma unroll
  for (int off = 1; off < 64; off <<= 1) {
    s += __shfl_xor(s, off, 64);
    s2 += __shfl_xor(s2, off, 64);
  }
  __shared__ float red[8];
  int wave = tid >> 6, lane = tid & 63;
  if (lane == 0) { red[wave] = s; red[4 + wave] = s2; }
  __syncthreads();
  s = red[0] + red[1] + red[2] + red[3];
  s2 = red[4] + red[5] + red[6] + red[7];
  const float mu = s * (1.f / 768.f);
  const float rstd = rsqrtf(s2 * (1.f / 768.f) - mu * mu + 1e-5f);
  float vv[3] = {v0, v1, v2};
#pragma unroll
  for (int e = 0; e < 3; ++e) {
    int col = tid + e * 256;
    float y = (vv[e] - mu) * rstd * g[col] + be[col];
    outF[(size_t)row * Dz + col] = y;
    if (outB) outB[(size_t)row * Dz + col] = f2b(y);
  }
}

// ---------------- launch ----------------
extern "C" void kernel_launch(void* const* d_in, const int* in_sizes, int n_in,
                              void* d_out, int out_size, void* d_ws,
                              size_t ws_size, hipStream_t stream) {
  const float* x   = (const float*)d_in[0];
  const int*   msk = (const int*)d_in[1];
  const float* Wq  = (const float*)d_in[2];
  const float* bq  = (const float*)d_in[3];
  const float* Wk  = (const float*)d_in[4];
  const float* bk  = (const float*)d_in[5];
  const float* Wv  = (const float*)d_in[6];
  const float* bv  = (const float*)d_in[7];
  const float* Wo  = (const float*)d_in[8];
  const float* bo  = (const float*)d_in[9];
  const float* g1  = (const float*)d_in[10];
  const float* be1 = (const float*)d_in[11];
  const float* W1  = (const float*)d_in[12];
  const float* b1  = (const float*)d_in[13];
  const float* W2  = (const float*)d_in[14];
  const float* b2  = (const float*)d_in[15];
  const float* g2  = (const float*)d_in[16];
  const float* be2 = (const float*)d_in[17];
  float* out = (float*)d_out;

  char* ws = (char*)d_ws;
  u16*   xb    = (u16*)(ws + 0);
  u16*   wqkvb = (u16*)(ws + 12582912);   // [2304][768] bf16 (transposed)
  u16*   wob   = (u16*)(ws + 16121856);   // [768][768]
  u16*   w1b   = (u16*)(ws + 17301504);   // [1536][768]
  u16*   w2b   = (u16*)(ws + 19660800);   // [768][1536]
  u16*   qb    = (u16*)(ws + 22020096);
  u16*   kb    = (u16*)(ws + 34603008);
  u16*   vtb   = (u16*)(ws + 47185920);
  u16*   ctx   = (u16*)(ws + 59768832);
  float* att   = (float*)(ws + 72351744);
  float* hf    = (float*)(ws + 97517568);
  u16*   hb    = (u16*)(ws + 122683392);
  u16*   f1    = (u16*)(ws + 47185920);  // reuse vt+ctx (dead after O-proj)
  float* yy    = (float*)(ws + 22020096); // reuse q+k (dead after attention)

  cvt4<<<6291456 / 4 / 256, 256, 0, stream>>>(x, xb, 6291456 / 4);
  wtrans<<<dim3(2304 / 32, 768 / 32), 256, 0, stream>>>(Wq, Wk, Wv, wqkvb, 768,
                                                        2304, 768);
  wtrans<<<dim3(24, 24), 256, 0, stream>>>(Wo, nullptr, nullptr, wob, 768, 768,
                                           768);
  wtrans<<<dim3(48, 24), 256, 0, stream>>>(W1, nullptr, nullptr, w1b, 768, 1536,
                                           1536);
  wtrans<<<dim3(24, 48), 256, 0, stream>>>(W2, nullptr, nullptr, w2b, 1536, 768,
                                           768);

  // QKV: [8192x768] @ [768x2304]
  gemm_k<0><<<dim3(2304 / 128, 8192 / 128), 256, 0, stream>>>(
      xb, wqkvb, 8192, 2304, 768, bq, bk, bv, nullptr, nullptr, nullptr, qb, kb,
      vtb);
  // attention
  attn_k<<<dim3(Sz / 64, Bz * Hz), 256, 0, stream>>>(qb, kb, vtb, msk, ctx);
  // O-proj + residual x -> att (fp32)
  gemm_k<1><<<dim3(768 / 128, 8192 / 128), 256, 0, stream>>>(
      ctx, wob, 8192, 768, 768, bo, nullptr, nullptr, x, att, nullptr, nullptr,
      nullptr, nullptr);
  // LN1 -> hf (fp32) + hb (bf16)
  ln_k<<<8192, 256, 0, stream>>>(att, g1, be1, hf, hb);
  // FFN1 + relu -> f1 (bf16)
  gemm_k<2><<<dim3(1536 / 128, 8192 / 128), 256, 0, stream>>>(
      hb, w1b, 8192, 1536, 768, b1, nullptr, nullptr, nullptr, nullptr, f1,
      nullptr, nullptr, nullptr);
  // FFN2 + residual hf -> yy (fp32)
  gemm_k<1><<<dim3(768 / 128, 8192 / 128), 256, 0, stream>>>(
      f1, w2b, 8192, 768, 1536, b2, nullptr, nullptr, hf, yy, nullptr, nullptr,
      nullptr, nullptr);
  // LN2 -> out
  ln_k<<<8192, 256, 0, stream>>>(yy, g2, be2, out, nullptr);
}

// Round 5
// 390.155 us; speedup vs baseline: 1.0213x; 1.0213x over previous
//
#include <hip/hip_runtime.h>
#include <cstdint>
#include <cstddef>

typedef unsigned short u16;
typedef __attribute__((ext_vector_type(8))) __bf16 bf16x8;
typedef __attribute__((ext_vector_type(4))) float floatx4;

#define Bz 8
#define Sz 1024
#define Dz 768
#define Hz 12
#define DHz 64

__device__ __forceinline__ u16 f2b(float f) {
  unsigned u = __float_as_uint(f);
  return (u16)((u + 0x7fffu + ((u >> 16) & 1u)) >> 16);
}

__device__ __forceinline__ bf16x8 ld8(const u16* p) {
  union { uint4 u; bf16x8 b; } t;
  t.u = *reinterpret_cast<const uint4*>(p);
  return t.b;
}

// async global->LDS, 16B per lane; lds base must be wave-uniform (HW adds lane*16)
__device__ __forceinline__ void load_lds16(const u16* g, u16* l) {
  __builtin_amdgcn_global_load_lds(
      (const __attribute__((address_space(1))) unsigned int*)g,
      (__attribute__((address_space(3))) unsigned int*)l, 16, 0, 0);
}

// ---------------- conversions ----------------
__global__ __launch_bounds__(256) void cvt4(const float* __restrict__ src,
                                            u16* __restrict__ dst, int n4) {
  int i = blockIdx.x * 256 + threadIdx.x;
  if (i >= n4) return;
  float4 v = reinterpret_cast<const float4*>(src)[i];
  union { u16 s[4]; uint2 u; } t;
  t.s[0] = f2b(v.x); t.s[1] = f2b(v.y); t.s[2] = f2b(v.z); t.s[3] = f2b(v.w);
  reinterpret_cast<uint2*>(dst)[i] = t.u;
}

// transpose fp32 [K][N] -> bf16 [N][K]; for QKV pack s1/s2 select by column
__global__ __launch_bounds__(256)
void wtrans(const float* __restrict__ s0, const float* __restrict__ s1,
            const float* __restrict__ s2, u16* __restrict__ dst,
            int K, int N, int srcN) {
  __shared__ float T[32][33];
  const int tx = threadIdx.x & 31, ty = threadIdx.x >> 5;
  const int n0 = blockIdx.x * 32, k0 = blockIdx.y * 32;
  const int n = n0 + tx;
  const float* src = s0;
  int nn = n;
  if (s1 && n >= 1536) { src = s2; nn = n - 1536; }
  else if (s1 && n >= 768) { src = s1; nn = n - 768; }
#pragma unroll
  for (int i = 0; i < 4; ++i)
    T[ty + i * 8][tx] = src[(size_t)(k0 + ty + i * 8) * srcN + nn];
  __syncthreads();
#pragma unroll
  for (int i = 0; i < 4; ++i)
    dst[(size_t)(n0 + ty + i * 8) * K + k0 + tx] = f2b(T[tx][ty + i * 8]);
}

// ---------------- GEMM (B^T input): C = A(MxK) * Bt(NxK)^T + epilogue ------
// Pipelined K-loop, prefetch ordered AFTER the frag ds_reads so the
// compiler's conservative auto `s_waitcnt vmcnt(0)` before ds_read sees zero
// outstanding loads (R4's order drained the just-issued prefetch each iter).
// EPI 0: QKV scatter; EPI 1: bias0 + resid (fp32) -> outF; EPI 2: bias0+relu->outB
template <int EPI>
__global__ __launch_bounds__(256, 4)
void gemm_k(const u16* __restrict__ A, const u16* __restrict__ Bt,
            int M, int N, int K,
            const float* __restrict__ bias0, const float* __restrict__ bias1,
            const float* __restrict__ bias2, const float* __restrict__ resid,
            float* __restrict__ outF, u16* __restrict__ outB,
            u16* __restrict__ qO, u16* __restrict__ kO, u16* __restrict__ vtO) {
  __shared__ __align__(16) u16 As[2][128 * 32];
  __shared__ __align__(16) u16 Bs[2][128 * 32];
  const int tid = threadIdx.x;
  const int lane = tid & 63, wave = tid >> 6;
  const int l15 = lane & 15, quad = lane >> 4;
  const int m0 = blockIdx.y * 128, n0 = blockIdx.x * 128;
  const int wm = (wave >> 1) * 64, wn = (wave & 1) * 64;

  floatx4 acc[4][4];
#pragma unroll
  for (int i = 0; i < 4; ++i)
#pragma unroll
    for (int j = 0; j < 4; ++j) acc[i][j] = {0.f, 0.f, 0.f, 0.f};

  const int srow = lane >> 2;          // + (wave*2+j)*16
  const int scol = (lane & 3) * 8;
  const u16* pA = A + (size_t)(m0 + wave * 32 + srow) * K + scol;
  const u16* pB = Bt + (size_t)(n0 + wave * 32 + srow) * K + scol;

  // prologue: stage tile 0 into buf 0 (4 loads/thread in flight)
#pragma unroll
  for (int j = 0; j < 2; ++j) {
    load_lds16(pA + (size_t)(j * 16) * K, &As[0][(wave * 2 + j) * 512]);
    load_lds16(pB + (size_t)(j * 16) * K, &Bs[0][(wave * 2 + j) * 512]);
  }

  const int NIT = K >> 5;
  for (int i = 0; i < NIT; ++i) {
    const int cur = i & 1;
    // own tile-i loads landed (issued one full iteration ago -> cheap wait);
    // required BEFORE the barrier for cross-wave LDS visibility.
    asm volatile("s_waitcnt vmcnt(0)" ::: "memory");
    // all waves' tile-i in LDS; all waves consumed buf[cur^1] frags last iter
    __builtin_amdgcn_s_barrier();
    bf16x8 af[4], bf[4];
#pragma unroll
    for (int ii = 0; ii < 4; ++ii)
      af[ii] = ld8(&As[cur][(wm + ii * 16 + l15) * 32 + quad * 8]);
#pragma unroll
    for (int j = 0; j < 4; ++j)
      bf[j] = ld8(&Bs[cur][(wn + j * 16 + l15) * 32 + quad * 8]);
    // keep the prefetch BELOW the ds_reads in the final schedule
    __builtin_amdgcn_sched_barrier(0);
    if (i + 1 < NIT) {
      const int k1 = (i + 1) << 5;
#pragma unroll
      for (int j = 0; j < 2; ++j) {
        load_lds16(pA + (size_t)(j * 16) * K + k1, &As[cur ^ 1][(wave * 2 + j) * 512]);
        load_lds16(pB + (size_t)(j * 16) * K + k1, &Bs[cur ^ 1][(wave * 2 + j) * 512]);
      }
    }
#pragma unroll
    for (int ii = 0; ii < 4; ++ii)
#pragma unroll
      for (int j = 0; j < 4; ++j)
        acc[ii][j] = __builtin_amdgcn_mfma_f32_16x16x32_bf16(af[ii], bf[j],
                                                             acc[ii][j], 0, 0, 0);
  }

#pragma unroll
  for (int i = 0; i < 4; ++i) {
    int mbase = m0 + wm + i * 16 + quad * 4;
#pragma unroll
    for (int j = 0; j < 4; ++j) {
      int n = n0 + wn + j * 16 + l15;
#pragma unroll
      for (int r = 0; r < 4; ++r) {
        int mm = mbase + r;
        float v = acc[i][j][r];
        if (EPI == 0) {
          if (n < 768) {
            v += bias0[n];
            qO[(size_t)mm * 768 + n] = f2b(v);
          } else if (n < 1536) {
            v += bias1[n - 768];
            kO[(size_t)mm * 768 + (n - 768)] = f2b(v);
          } else {
            int d = n - 1536;
            v += bias2[d];
            int hh = d >> 6, dh = d & 63;
            int bb = mm >> 10, ss = mm & 1023;
            vtO[((size_t)(bb * Hz + hh) * DHz + dh) * Sz + ss] = f2b(v);
          }
        } else if (EPI == 1) {
          v += bias0[n] + resid[(size_t)mm * N + n];
          outF[(size_t)mm * N + n] = v;
        } else {
          v += bias0[n];
          v = fmaxf(v, 0.f);
          outB[(size_t)mm * N + n] = f2b(v);
        }
      }
    }
  }
}

// ---------------- flash attention (LDS-staged K/V tiles) ----------------
__global__ __launch_bounds__(256, 3)
void attn_k(const u16* __restrict__ q, const u16* __restrict__ kbuf,
            const u16* __restrict__ vt, const int* __restrict__ mask,
            u16* __restrict__ ctx) {
  __shared__ float addend[Sz];
  __shared__ __align__(16) u16 Ks[128 * 64];
  __shared__ __align__(16) u16 Vs[64 * 128];
  __shared__ __align__(16) u16 P[4][16][132];
  const int tid = threadIdx.x;
  const int wave = tid >> 6, lane = tid & 63;
  const int l15 = lane & 15, quad = lane >> 4;
  const int bq = blockIdx.x;
  const int b = blockIdx.y / Hz, h = blockIdx.y % Hz;

  for (int s = tid; s < Sz; s += 256)
    addend[s] = mask[b * Sz + s] ? 0.f : -1e9f;

  const int qrow = bq * 64 + wave * 16 + l15;
  const u16* qp = q + (size_t)(b * Sz + qrow) * Dz + h * DHz;
  const bf16x8 fq0 = ld8(qp + quad * 8);
  const bf16x8 fq1 = ld8(qp + 32 + quad * 8);

  const int kchunk = (lane & 7) ^ (lane >> 3);
  const int l7 = l15 & 7;
  const int s0q = quad ^ l7;

  float m_l = -1e30f, l_l = 0.f;
  floatx4 o[4];
#pragma unroll
  for (int nt = 0; nt < 4; ++nt) o[nt] = {0.f, 0.f, 0.f, 0.f};

  const size_t vbase = (size_t)(b * Hz + h) * DHz * Sz;

  for (int kt = 0; kt < Sz / 128; ++kt) {
    __syncthreads();
#pragma unroll
    for (int j = 0; j < 4; ++j) {
      const int key = wave * 32 + j * 8 + (lane >> 3);
      load_lds16(kbuf + (size_t)(b * Sz + kt * 128 + key) * Dz + h * DHz +
                     kchunk * 8,
                 Ks + wave * 2048 + j * 512);
      const int dh = wave * 16 + j * 4 + (lane >> 4);
      const int vchunk = (lane & 15) ^ (dh & 7);
      load_lds16(vt + vbase + (size_t)dh * Sz + kt * 128 + vchunk * 8,
                 Vs + wave * 2048 + j * 512);
    }
    __syncthreads();

    floatx4 z[8];
#pragma unroll
    for (int t = 0; t < 8; ++t) {
      const int krow = t * 16 + l15;
      bf16x8 fk0 = ld8(&Ks[krow * 64 + s0q * 8]);
      bf16x8 fk1 = ld8(&Ks[krow * 64 + (s0q ^ 4) * 8]);
      floatx4 zz = {0.f, 0.f, 0.f, 0.f};
      zz = __builtin_amdgcn_mfma_f32_16x16x32_bf16(fk0, fq0, zz, 0, 0, 0);
      zz = __builtin_amdgcn_mfma_f32_16x16x32_bf16(fk1, fq1, zz, 0, 0, 0);
      const float4 ad =
          *reinterpret_cast<const float4*>(&addend[kt * 128 + t * 16 + quad * 4]);
      z[t][0] = zz[0] * 0.125f + ad.x;
      z[t][1] = zz[1] * 0.125f + ad.y;
      z[t][2] = zz[2] * 0.125f + ad.z;
      z[t][3] = zz[3] * 0.125f + ad.w;
    }
    float mx = z[0][0];
#pragma unroll
    for (int t = 0; t < 8; ++t)
#pragma unroll
      for (int r = 0; r < 4; ++r) mx = fmaxf(mx, z[t][r]);
    mx = fmaxf(mx, __shfl_xor(mx, 16, 64));
    mx = fmaxf(mx, __shfl_xor(mx, 32, 64));
    const float nm = fmaxf(m_l, mx);
    const float alpha = __expf(m_l - nm);
    m_l = nm;
    float su = 0.f;
#pragma unroll
    for (int t = 0; t < 8; ++t) {
      union { u16 s[4]; uint2 u; } pk;
#pragma unroll
      for (int r = 0; r < 4; ++r) {
        float p = __expf(z[t][r] - nm);
        su += p;
        pk.s[r] = f2b(p);
      }
      *reinterpret_cast<uint2*>(&P[wave][l15][t * 16 + quad * 4]) = pk.u;
    }
    su += __shfl_xor(su, 16, 64);
    su += __shfl_xor(su, 32, 64);
    l_l = l_l * alpha + su;
    float av[4];
#pragma unroll
    for (int r = 0; r < 4; ++r) av[r] = __shfl(alpha, quad * 4 + r, 64);
#pragma unroll
    for (int nt = 0; nt < 4; ++nt)
#pragma unroll
      for (int r = 0; r < 4; ++r) o[nt][r] *= av[r];
    bf16x8 ap[4];
#pragma unroll
    for (int c = 0; c < 4; ++c)
      ap[c] = ld8(&P[wave][l15][c * 32 + quad * 8]);
#pragma unroll
    for (int nt = 0; nt < 4; ++nt) {
#pragma unroll
      for (int c = 0; c < 4; ++c) {
        bf16x8 bv =
            ld8(&Vs[(nt * 16 + l15) * 128 + (((c * 4 + quad) ^ l7) * 8)]);
        o[nt] = __builtin_amdgcn_mfma_f32_16x16x32_bf16(ap[c], bv, o[nt], 0, 0, 0);
      }
    }
  }

  const float linv = 1.f / l_l;
  float lv[4];
#pragma unroll
  for (int r = 0; r < 4; ++r) lv[r] = __shfl(linv, quad * 4 + r, 64);
  const int qr = bq * 64 + wave * 16 + quad * 4;
#pragma unroll
  for (int nt = 0; nt < 4; ++nt)
#pragma unroll
    for (int r = 0; r < 4; ++r) {
      float v = o[nt][r] * lv[r];
      ctx[(size_t)(b * Sz + qr + r) * Dz + h * DHz + nt * 16 + l15] = f2b(v);
    }
}

// ---------------- layernorm (row = 768) ----------------
__global__ __launch_bounds__(256)
void ln_k(const float* __restrict__ in, const float* __restrict__ g,
          const float* __restrict__ be, float* __restrict__ outF,
          u16* __restrict__ outB) {
  const int row = blockIdx.x;
  const float* x = in + (size_t)row * Dz;
  const int tid = threadIdx.x;
  float v0 = x[tid], v1 = x[tid + 256], v2 = x[tid + 512];
  float s = v0 + v1 + v2;
  float s2 = v0 * v0 + v1 * v1 + v2 * v2;
#pragma unroll
  for (int off = 1; off < 64; off <<= 1) {
    s += __shfl_xor(s, off, 64);
    s2 += __shfl_xor(s2, off, 64);
  }
  __shared__ float red[8];
  int wave = tid >> 6, lane = tid & 63;
  if (lane == 0) { red[wave] = s; red[4 + wave] = s2; }
  __syncthreads();
  s = red[0] + red[1] + red[2] + red[3];
  s2 = red[4] + red[5] + red[6] + red[7];
  const float mu = s * (1.f / 768.f);
  const float rstd = rsqrtf(s2 * (1.f / 768.f) - mu * mu + 1e-5f);
  float vv[3] = {v0, v1, v2};
#pragma unroll
  for (int e = 0; e < 3; ++e) {
    int col = tid + e * 256;
    float y = (vv[e] - mu) * rstd * g[col] + be[col];
    outF[(size_t)row * Dz + col] = y;
    if (outB) outB[(size_t)row * Dz + col] = f2b(y);
  }
}

// ---------------- launch ----------------
extern "C" void kernel_launch(void* const* d_in, const int* in_sizes, int n_in,
                              void* d_out, int out_size, void* d_ws,
                              size_t ws_size, hipStream_t stream) {
  const float* x   = (const float*)d_in[0];
  const int*   msk = (const int*)d_in[1];
  const float* Wq  = (const float*)d_in[2];
  const float* bq  = (const float*)d_in[3];
  const float* Wk  = (const float*)d_in[4];
  const float* bk  = (const float*)d_in[5];
  const float* Wv  = (const float*)d_in[6];
  const float* bv  = (const float*)d_in[7];
  const float* Wo  = (const float*)d_in[8];
  const float* bo  = (const float*)d_in[9];
  const float* g1  = (const float*)d_in[10];
  const float* be1 = (const float*)d_in[11];
  const float* W1  = (const float*)d_in[12];
  const float* b1  = (const float*)d_in[13];
  const float* W2  = (const float*)d_in[14];
  const float* b2  = (const float*)d_in[15];
  const float* g2  = (const float*)d_in[16];
  const float* be2 = (const float*)d_in[17];
  float* out = (float*)d_out;

  char* ws = (char*)d_ws;
  u16*   xb    = (u16*)(ws + 0);
  u16*   wqkvb = (u16*)(ws + 12582912);   // [2304][768] bf16 (transposed)
  u16*   wob   = (u16*)(ws + 16121856);   // [768][768]
  u16*   w1b   = (u16*)(ws + 17301504);   // [1536][768]
  u16*   w2b   = (u16*)(ws + 19660800);   // [768][1536]
  u16*   qb    = (u16*)(ws + 22020096);
  u16*   kb    = (u16*)(ws + 34603008);
  u16*   vtb   = (u16*)(ws + 47185920);
  u16*   ctx   = (u16*)(ws + 59768832);
  float* att   = (float*)(ws + 72351744);
  float* hf    = (float*)(ws + 97517568);
  u16*   hb    = (u16*)(ws + 122683392);
  u16*   f1    = (u16*)(ws + 47185920);  // reuse vt+ctx (dead after O-proj)
  float* yy    = (float*)(ws + 22020096); // reuse q+k (dead after attention)

  cvt4<<<6291456 / 4 / 256, 256, 0, stream>>>(x, xb, 6291456 / 4);
  wtrans<<<dim3(2304 / 32, 768 / 32), 256, 0, stream>>>(Wq, Wk, Wv, wqkvb, 768,
                                                        2304, 768);
  wtrans<<<dim3(24, 24), 256, 0, stream>>>(Wo, nullptr, nullptr, wob, 768, 768,
                                           768);
  wtrans<<<dim3(48, 24), 256, 0, stream>>>(W1, nullptr, nullptr, w1b, 768, 1536,
                                           1536);
  wtrans<<<dim3(24, 48), 256, 0, stream>>>(W2, nullptr, nullptr, w2b, 1536, 768,
                                           768);

  // QKV: [8192x768] @ [768x2304]
  gemm_k<0><<<dim3(2304 / 128, 8192 / 128), 256, 0, stream>>>(
      xb, wqkvb, 8192, 2304, 768, bq, bk, bv, nullptr, nullptr, nullptr, qb, kb,
      vtb);
  // attention
  attn_k<<<dim3(Sz / 64, Bz * Hz), 256, 0, stream>>>(qb, kb, vtb, msk, ctx);
  // O-proj + residual x -> att (fp32)
  gemm_k<1><<<dim3(768 / 128, 8192 / 128), 256, 0, stream>>>(
      ctx, wob, 8192, 768, 768, bo, nullptr, nullptr, x, att, nullptr, nullptr,
      nullptr, nullptr);
  // LN1 -> hf (fp32) + hb (bf16)
  ln_k<<<8192, 256, 0, stream>>>(att, g1, be1, hf, hb);
  // FFN1 + relu -> f1 (bf16)
  gemm_k<2><<<dim3(1536 / 128, 8192 / 128), 256, 0, stream>>>(
      hb, w1b, 8192, 1536, 768, b1, nullptr, nullptr, nullptr, nullptr, f1,
      nullptr, nullptr, nullptr);
  // FFN2 + residual hf -> yy (fp32)
  gemm_k<1><<<dim3(768 / 128, 8192 / 128), 256, 0, stream>>>(
      f1, w2b, 8192, 768, 1536, b2, nullptr, nullptr, hf, yy, nullptr, nullptr,
      nullptr, nullptr);
  // LN2 -> out
  ln_k<<<8192, 256, 0, stream>>>(yy, g2, be2, out, nullptr);
}